// Round 10
// baseline (446.830 us; speedup 1.0000x reference)
//
#include <hip/hip_runtime.h>
#include <hip/hip_bf16.h>

// SparseMOE on MI355X — round 17b: RESUBMIT of r17 (256x256 GEMM tile).
// r17 bench died with "container failed twice" — same infra signature as
// Round 0, where a harness-proven kernel failed then passed on resubmit.
// Audit found no deadlock (uniform barriers), no OOB (all indices bounded),
// LDS 96KB@512thr is within the guide's verified 128KB/512thr envelope,
// VGPR ~200 < 256 cap. Resubmitting unchanged.
// --- r17 rationale ---
// 128^2 tile moves 557 MB/gemm of L2->LDS staging (64 FLOP/B) = staging-BW
// roofline at 62 us / MfmaUtil 22% (r14/r15: depth & occupancy don't move it).
// 256x256 tile doubles arithmetic intensity (275 MB/gemm):
//  * 512 threads / 8 waves; wave (wr,wc) owns 128x64 output (acc[8][4] f32x4).
//  * 3-buf LDS 96 KB; r15 single-barrier protocol: vmcnt(4) -> barrier ->
//    STAGE((kt+2)%3 = buf of kt-1, reads finished pre-barrier) -> MFMA.
//  * chunk-XOR swizzle both-sides; setprio around MFMA cluster.
//  * epilogue via LDS in two 64KB halves -> dwordx4 streaming stores.
// Per-element MFMA K-chain identical -> bitwise-same math. Everything else r16.

#define HDIM 1024
#define NEXP 8
#define BM 256
#define BN 256
#define BK 32
#define HH ((size_t)HDIM * HDIM)

typedef __hip_bfloat16 bf16;
typedef unsigned short ushort_t;
typedef __attribute__((ext_vector_type(8))) short bf16x8;
typedef __attribute__((ext_vector_type(4))) float f32x4;

__device__ __forceinline__ float bflo(unsigned u) { return __uint_as_float(u << 16); }
__device__ __forceinline__ float bfhi(unsigned u) { return __uint_as_float(u & 0xffff0000u); }
__device__ __forceinline__ unsigned short f2bfu(float f) {
  bf16 h = __float2bfloat16(f);
  return *reinterpret_cast<unsigned short*>(&h);
}
__device__ __forceinline__ int iclamp(int v, int lo, int hi) {
  return v < lo ? lo : (v > hi ? hi : v);
}

// async global->LDS, 16B/lane; LDS dest is wave-uniform base + lane*16
__device__ __forceinline__ void async_cp16(const void* g, void* l) {
  __builtin_amdgcn_global_load_lds((const __attribute__((address_space(1))) void*)g,
                                   (__attribute__((address_space(3))) void*)l,
                                   16, 0, 0);
}

// load 4 consecutive elements (idx multiple of 4) as floats, dtype-flagged
__device__ __forceinline__ void ld4f(const void* base, size_t idx, bool f32, float o[4]) {
  if (f32) {
    float4 v = *(const float4*)((const float*)base + idx);
    o[0] = v.x; o[1] = v.y; o[2] = v.z; o[3] = v.w;
  } else {
    uint2 v = *(const uint2*)((const unsigned short*)base + idx);
    o[0] = bflo(v.x); o[1] = bfhi(v.x); o[2] = bflo(v.y); o[3] = bfhi(v.y);
  }
}

// ------- sniff + init merged: blocks 0-4 sniff (plain store), 5-16 zero meta -------
__global__ void k_sniff(const ushort_t* a0, int n0, const ushort_t* a1, int n1,
                        const ushort_t* a2, int n2, const ushort_t* a3, int n3,
                        const ushort_t* a4, int n4, int* __restrict__ meta) {
  int b = blockIdx.x;
  int tid = threadIdx.x;
  if (b >= 5) {
    int idx = (b - 5) * 256 + tid;           // 0..3071 covers 3067 items
    int i = idx < 2048 ? idx : idx + 5;      // skip flags range [2048,2053)
    if (i < 3072) meta[i] = 0;
    return;
  }
  const ushort_t* a = b == 0 ? a0 : b == 1 ? a1 : b == 2 ? a2 : b == 3 ? a3 : a4;
  int n = b == 0 ? n0 : b == 1 ? n1 : b == 2 ? n2 : b == 3 ? n3 : n4;
  int hits = 0;
  for (int i = tid; i < n; i += 256) {
    ushort_t v = a[i];
    if ((v & 0x7F80) == 0x7F80) hits++;      // bf16 NaN/Inf exponent pattern
  }
  __shared__ int red[256];
  red[tid] = hits;
  __syncthreads();
  for (int off = 128; off >= 1; off >>= 1) {
    if (tid < off) red[tid] += red[tid + off];
    __syncthreads();
  }
  if (tid == 0) meta[2048 + b] = red[0];     // plain store
}

// ---------------- router: 1 wave/token, LDS-transposed gate, NO atomics ----------------
// meta ints: [0,512)=cnt[s][e], [512,1024)=fill[s][e], [1024,1536)=segbase[s][e],
//            [2048,2053)=dtype flags {x,gw,w1,w2,w3}, [2560,2624)=ntiles[s]
__global__ __launch_bounds__(512) void k_router(
    const void* __restrict__ x, const void* __restrict__ gw,
    const bf16* __restrict__ gb, void* __restrict__ dout, bf16* __restrict__ xb,
    int* __restrict__ sel_e, float* __restrict__ sel_w,
    int* __restrict__ meta, int TS, int T) {
  __shared__ float sgT[NEXP][HDIM];            // 32 KB gate, TRANSPOSED [e][h]
  const int* flags = meta + 2048;
  bool fx = flags[0] != 0, fgw = flags[1] != 0;
  int tid = threadIdx.x;

#pragma unroll
  for (int r = 0; r < 2; r++) {
    int h = r * 512 + tid;
    float g[8];
    ld4f(gw, (size_t)h * NEXP, fgw, g);
    ld4f(gw, (size_t)h * NEXP + 4, fgw, g + 4);
#pragma unroll
    for (int e = 0; e < NEXP; e++) sgT[e][h] = g[e];
  }
  __syncthreads();

  int wave = tid >> 6, lane = tid & 63;
  int t = blockIdx.x * 8 + wave;

  double acc[NEXP];
#pragma unroll
  for (int e = 0; e < NEXP; e++) acc[e] = 0.0;

  if (t < T) {
#pragma unroll
    for (int j = 0; j < 4; j++) {
      int h = j * 256 + lane * 4;
      float xf[4];
      ld4f(x, (size_t)t * HDIM + h, fx, xf);
      if (fx) {   // only materialize bf16 copy when x is fp32
        uint2 ov;
        ov.x = (unsigned)f2bfu(xf[0]) | ((unsigned)f2bfu(xf[1]) << 16);
        ov.y = (unsigned)f2bfu(xf[2]) | ((unsigned)f2bfu(xf[3]) << 16);
        *(uint2*)((unsigned short*)xb + (size_t)t * HDIM + h) = ov;
      }
#pragma unroll
      for (int e = 0; e < NEXP; e++) {
        float4 g = *(const float4*)&sgT[e][h];
        acc[e] += (double)xf[0] * (double)g.x + (double)xf[1] * (double)g.y
                + (double)xf[2] * (double)g.z + (double)xf[3] * (double)g.w;
      }
    }
  }

#pragma unroll
  for (int off = 32; off >= 1; off >>= 1) {
#pragma unroll
    for (int e = 0; e < NEXP; e++) acc[e] += __shfl_down(acc[e], off);
  }

  if (lane == 0 && t < T) {
    double l[NEXP];
#pragma unroll
    for (int e = 0; e < NEXP; e++) l[e] = acc[e] + (double)__bfloat162float(gb[e]);
    size_t lo = (size_t)T * HDIM + (size_t)t * NEXP;
    if (fx) {
      float* lp = (float*)dout + lo;
#pragma unroll
      for (int e = 0; e < NEXP; e++) lp[e] = (float)l[e];
    } else {
      unsigned short* lp = (unsigned short*)dout + lo;
#pragma unroll
      for (int e = 0; e < NEXP; e++) lp[e] = f2bfu((float)l[e]);
    }
    int i1 = 0; double v1 = l[0];
#pragma unroll
    for (int e = 1; e < NEXP; e++) if (l[e] > v1) { v1 = l[e]; i1 = e; }
    int i2 = -1; double v2 = -1e300;
#pragma unroll
    for (int e = 0; e < NEXP; e++) if (e != i1 && l[e] > v2) { v2 = l[e]; i2 = e; }
    if (i2 < 0) i2 = (i1 + 1) & 7;               // defensive
    float w1 = 1.0f / (1.0f + __expf((float)(v2 - v1)));
    sel_e[2 * t] = i1; sel_e[2 * t + 1] = i2;
    sel_w[2 * t] = w1; sel_w[2 * t + 1] = 1.0f - w1;
  }
}

// ------- offsets: histogram sel_e locally, BM-aligned segments, row map, pads -------
__global__ void k_offsets(const int* __restrict__ sel_e, int* __restrict__ meta,
                          int* __restrict__ list, int* __restrict__ row_e,
                          int RCAP, int NTMAX, int TS) {
  int s = blockIdx.x;
  __shared__ int base[NEXP + 1];
  __shared__ int wsum[4][NEXP];
  int tid = threadIdx.x;

  int cnt[NEXP];
#pragma unroll
  for (int e = 0; e < NEXP; e++) cnt[e] = 0;
  const int* se = sel_e + (size_t)2 * s * TS;
  for (int i = tid; i < 2 * TS; i += 256) {
    int v = se[i];
#pragma unroll
    for (int e = 0; e < NEXP; e++) cnt[e] += (v == e) ? 1 : 0;
  }
#pragma unroll
  for (int off = 32; off >= 1; off >>= 1)
#pragma unroll
    for (int e = 0; e < NEXP; e++) cnt[e] += __shfl_down(cnt[e], off);
  int lane = tid & 63, wave = tid >> 6;
  if (lane == 0) {
#pragma unroll
    for (int e = 0; e < NEXP; e++) wsum[wave][e] = cnt[e];
  }
  __syncthreads();

  if (tid == 0) {
    int b = 0;
    for (int e = 0; e < NEXP; e++) {
      int ce = wsum[0][e] + wsum[1][e] + wsum[2][e] + wsum[3][e];
      base[e] = b;
      meta[s * 8 + e] = ce;
      meta[512 + s * 8 + e] = b;               // fill counter
      meta[1024 + s * 8 + e] = b;              // segment base (rows)
      b = (b + ce + BM - 1) & ~(BM - 1);
    }
    base[NEXP] = b;
    meta[2560 + s] = b / BM;                   // total tiles this split
  }
  __syncthreads();

  for (int r = tid; r < NTMAX; r += blockDim.x) {
    int rs = r * BM;
    int e = 0;
    for (int q = 1; q < NEXP; q++) if (rs >= base[q]) e = q;
    row_e[s * NTMAX + r] = e;
  }
  int* ls = list + (size_t)s * RCAP;
  for (int e = 0; e < NEXP; e++) {
    int ce = wsum[0][e] + wsum[1][e] + wsum[2][e] + wsum[3][e];
    for (int p = base[e] + ce + tid; p < base[e + 1]; p += blockDim.x)
      ls[p] = s * TS;        // pad rows gather a valid token; never combined
  }
}

// ------- scatter: two-level (LDS bin ranks + 8 global RMWs/block) -------
__global__ void k_scatter(const int* __restrict__ sel_e, int* __restrict__ meta,
                          int* __restrict__ list, int* __restrict__ pos_of,
                          int T, int TS, int RCAP) {
  __shared__ int lcnt[NEXP];
  __shared__ int lbase[NEXP];
  int tid = threadIdx.x;
  if (tid < NEXP) lcnt[tid] = 0;
  __syncthreads();
  int t = blockIdx.x * blockDim.x + tid;
  int s = (int)(((long long)blockIdx.x * blockDim.x) / TS);   // uniform per block
  int e0 = sel_e[2 * t], e1 = sel_e[2 * t + 1];
  int r0 = atomicAdd(&lcnt[e0], 1);
  int r1 = atomicAdd(&lcnt[e1], 1);
  __syncthreads();
  if (tid < NEXP) lbase[tid] = atomicAdd(&meta[512 + s * 8 + tid], lcnt[tid]);
  __syncthreads();
  int p0 = lbase[e0] + r0;
  int p1 = lbase[e1] + r1;
  if (p0 >= 0 && p0 < RCAP) list[(size_t)s * RCAP + p0] = t;
  if (p1 >= 0 && p1 < RCAP) list[(size_t)s * RCAP + p1] = t;
  pos_of[2 * t] = p0;
  pos_of[2 * t + 1] = p1;
}

// -------- transpose+convert, up to 3 layers in one dispatch: layer = z>>3 --------
__global__ void k_trans(const void* __restrict__ wa, const void* __restrict__ wb,
                        const void* __restrict__ wc, const int* __restrict__ flags,
                        bf16* __restrict__ wt) {
  int z = blockIdx.z;
  int layer = z >> 3, e = z & 7;
  const void* w = layer == 0 ? wa : layer == 1 ? wb : wc;
  bool fW = flags[2 + layer] != 0;
  bf16* wtl = wt + (size_t)layer * NEXP * HH;
  __shared__ unsigned short tile[32][33];
  int tid = threadIdx.x;
  int r = tid >> 3, c4 = (tid & 7) * 4;
  int R0 = blockIdx.y * 32, C0 = blockIdx.x * 32;
  float v[4];
  ld4f(w, (size_t)e * HH + (size_t)(R0 + r) * HDIM + C0 + c4, fW, v);
  tile[c4 + 0][r] = f2bfu(v[0]);
  tile[c4 + 1][r] = f2bfu(v[1]);
  tile[c4 + 2][r] = f2bfu(v[2]);
  tile[c4 + 3][r] = f2bfu(v[3]);
  __syncthreads();
  uint2 ov;
  ov.x = (unsigned)tile[r][c4 + 0] | ((unsigned)tile[r][c4 + 1] << 16);
  ov.y = (unsigned)tile[r][c4 + 2] | ((unsigned)tile[r][c4 + 3] << 16);
  *(uint2*)((unsigned short*)wtl + (size_t)e * HH + (size_t)(C0 + r) * HDIM + R0 + c4) = ov;
}

// ---- MFMA GEMM: 256x256 tile, 8 waves, 3-buf single-barrier pipeline ----
// A is ALWAYS bf16 (x-direct or xb for layer 1, h1/h2 for layers 2/3).
template <bool GATHER, bool RELU>
__global__ __launch_bounds__(512, 2) void k_gemm(
    const bf16* __restrict__ A, const bf16* __restrict__ Axb,
    const int* __restrict__ list,
    const int* __restrict__ row_e, const int* __restrict__ ntiles,
    const bf16* __restrict__ wt, const bf16* __restrict__ bias,
    bf16* __restrict__ C, const int* __restrict__ flags, int Tm1) {
  // XCD swizzle: ids sharing tm are gridDim.y apart (NTMAX % 8 == 0 -> same XCD).
  int id = blockIdx.y * gridDim.x + blockIdx.x;
  int tm = id % gridDim.y;
  int tn = id / gridDim.y;
  if (tm >= *ntiles) return;
  int e = row_e[tm];
  int row0 = tm * BM;
  const bf16* Ause = (GATHER && flags[0] != 0) ? Axb : A;  // fp32 x -> bf16 copy

  // 3 buffers x (A 16KB + B 16KB) = 96 KB; chunk-swizzled:
  // physical [row][c] holds logical [row][c^((row>>1)&3)]
  const int BUF = (BM + BN) * BK;                          // 16384 ushorts
  __shared__ __align__(16) unsigned short smem[3 * (BM + BN) * BK];

  int tid = threadIdx.x;
  int lane = tid & 63, wave = tid >> 6;                    // 8 waves
  // staging: lane -> 16 rows/wave/op, chunk lane&3; inverse-swizzled source:
  // (lane&3)^((r0>>1)&3) = (lane&3)^((lane>>3)&3)  (wave*16 contributes 0)
  int ksw = ((lane & 3) ^ ((lane >> 3) & 3)) * 8;   // elems
  int r0 = wave * 16 + (lane >> 2);                 // [0,128)

  const unsigned short* pb0 = (const unsigned short*)wt + (size_t)e * HH
                            + (size_t)(tn * BN + r0) * HDIM + ksw;
  const unsigned short* pb1 = pb0 + (size_t)128 * HDIM;
  const unsigned short* pa0;
  const unsigned short* pa1;
  if (GATHER) {
    // per-lane global source is legal for global_load_lds (measured m104/m108)
    int t0 = iclamp(list[row0 + r0], 0, Tm1);
    int t1 = iclamp(list[row0 + r0 + 128], 0, Tm1);
    pa0 = (const unsigned short*)Ause + (size_t)t0 * HDIM + ksw;
    pa1 = (const unsigned short*)Ause + (size_t)t1 * HDIM + ksw;
  } else {
    pa0 = (const unsigned short*)Ause + (size_t)(row0 + r0) * HDIM + ksw;
    pa1 = pa0 + (size_t)128 * HDIM;
  }
  unsigned short* laD0 = smem + (wave * 16) * BK;            // + p*BUF
  unsigned short* laD1 = laD0 + 128 * BK;
  unsigned short* lbD0 = smem + BM * BK + (wave * 16) * BK;  // + p*BUF
  unsigned short* lbD1 = lbD0 + 128 * BK;

#define STAGE(pb, ktt)                                         \
  do {                                                         \
    int _o = (pb) * BUF;                                       \
    async_cp16(pa0 + (size_t)(ktt) * BK, laD0 + _o);           \
    async_cp16(pa1 + (size_t)(ktt) * BK, laD1 + _o);           \
    async_cp16(pb0 + (size_t)(ktt) * BK, lbD0 + _o);           \
    async_cp16(pb1 + (size_t)(ktt) * BK, lbD1 + _o);           \
  } while (0)

  f32x4 acc[8][4];                                   // 128 VGPR accumulator
#pragma unroll
  for (int i = 0; i < 8; i++)
#pragma unroll
    for (int j = 0; j < 4; j++) acc[i][j] = (f32x4){0.f, 0.f, 0.f, 0.f};

  int lm = lane & 15, quad = lane >> 4;
  int wr = wave >> 2, wc = wave & 3;                 // wave -> 128x64 sub-tile
  int am = wr * 128, bn = wc * 64;
  // ds_read chunk: logical chunk = quad, row ≡ lm (mod 16) -> phys = quad^((lm>>1)&3)
  int rdc = (quad ^ ((lm >> 1) & 3)) * 8;            // elems

  STAGE(0, 0);
  STAGE(1, 1);

  const int NK = HDIM / BK;                          // 32
  for (int kt = 0; kt < NK; ++kt) {
    int p = kt % 3;
    // counted wait: tile kt's 4 stages retired (own-wave); single barrier makes
    // all waves' tile-kt data mutually visible. Stage kt+2 goes into the buffer
    // of tile kt-1, whose reads every wave completed BEFORE this barrier
    // (MFMA's lgkmcnt drained the ds_reads) -> race-free with one barrier.
    if (kt < NK - 1) asm volatile("s_waitcnt vmcnt(4)" ::: "memory");
    else             asm volatile("s_waitcnt vmcnt(0)" ::: "memory");
    __builtin_amdgcn_sched_barrier(0);
    __builtin_amdgcn_s_barrier();
    __builtin_amdgcn_sched_barrier(0);
    if (kt + 2 < NK) STAGE((kt + 2) % 3, kt + 2);

    int o = p * BUF;
    bf16x8 bfr[4];
#pragma unroll
    for (int j = 0; j < 4; j++)
      bfr[j] = *(const bf16x8*)&smem[o + BM * BK + (bn + j * 16 + lm) * BK + rdc];
    __builtin_amdgcn_s_setprio(1);
#pragma unroll
    for (int i = 0; i < 8; i++) {
      bf16x8 afi = *(const bf16x8*)&smem[o + (am + i * 16 + lm) * BK + rdc];
#pragma unroll
      for (int j = 0; j < 4; j++)
        acc[i][j] = __builtin_amdgcn_mfma_f32_16x16x32_bf16(afi, bfr[j], acc[i][j], 0, 0, 0);
    }
    __builtin_amdgcn_s_setprio(0);
  }
#undef STAGE

  // ---- epilogue: bias+relu -> LDS (64KB half-tiles) -> coalesced dwordx4 stores ----
  unsigned short* cst = smem;                        // 128x256 ushort = 64 KB
  unsigned short* Cg = (unsigned short*)C;
#pragma unroll
  for (int hh = 0; hh < 2; hh++) {
    __syncthreads();                                 // prior reads/stream done
    if (wr == hh) {
#pragma unroll
      for (int j = 0; j < 4; j++) {
        int col = bn + j * 16 + lm;                  // tile-local col [0,256)
        float bv = __bfloat162float(bias[e * HDIM + tn * BN + col]);  // zeros: dtype-safe
#pragma unroll
        for (int i = 0; i < 8; i++) {
          int rowl = i * 16 + quad * 4;              // [0,128)
#pragma unroll
          for (int rr = 0; rr < 4; rr++) {
            float v = acc[i][j][rr] + bv;
            if (RELU) v = fmaxf(v, 0.f);
            cst[(rowl + rr) * BN + col] = f2bfu(v);
          }
        }
      }
    }
    __syncthreads();
#pragma unroll
    for (int it = 0; it < 8; it++) {
      int o = it * 8192 + tid * 16;                  // byte offset into 64KB half
      int row = o >> 9;                              // 512 B per row (256 cols)
      int cole = (o & 511) >> 1;
      uint4 v = *(const uint4*)((const char*)cst + o);
      *(uint4*)&Cg[(size_t)(row0 + hh * 128 + row) * HDIM + tn * BN + cole] = v;
    }
  }
}

// ---------------- weighted combine: out[t] = w0*y[pos0] + w1*y[pos1] ----------------
__global__ void k_combine(const bf16* __restrict__ y, const int* __restrict__ pos_of,
                          const float* __restrict__ sel_w, void* __restrict__ dout,
                          size_t out_elem_off, const int* __restrict__ meta, int Pm1) {
  bool fx = meta[2048] != 0;                   // out dtype follows x
  int t = blockIdx.x;
  int tid = threadIdx.x;
  int p0 = iclamp(pos_of[2 * t], 0, Pm1);
  int p1 = iclamp(pos_of[2 * t + 1], 0, Pm1);
  float w0 = sel_w[2 * t], w1 = sel_w[2 * t + 1];
  int h = tid * 4;
  uint2 a = *(const uint2*)((const unsigned short*)y + (size_t)p0 * HDIM + h);
  uint2 b = *(const uint2*)((const unsigned short*)y + (size_t)p1 * HDIM + h);
  float o0 = w0 * bflo(a.x) + w1 * bflo(b.x);
  float o1 = w0 * bfhi(a.x) + w1 * bfhi(b.x);
  float o2 = w0 * bflo(a.y) + w1 * bflo(b.y);
  float o3 = w0 * bfhi(a.y) + w1 * bfhi(b.y);
  size_t off = out_elem_off + (size_t)t * HDIM + h;
  if (fx) {
    float4 ov = { o0, o1, o2, o3 };
    *(float4*)((float*)dout + off) = ov;
  } else {
    uint2 ov;
    ov.x = (unsigned)f2bfu(o0) | ((unsigned)f2bfu(o1) << 16);
    ov.y = (unsigned)f2bfu(o2) | ((unsigned)f2bfu(o3) << 16);
    *(uint2*)((unsigned short*)dout + off) = ov;
  }
}

extern "C" void kernel_launch(void* const* d_in, const int* in_sizes, int n_in,
                              void* d_out, int out_size, void* d_ws, size_t ws_size,
                              hipStream_t stream) {
  const void* x  = d_in[0];
  const void* gw = d_in[1];
  const bf16* gb = (const bf16*)d_in[2];
  const void* w1 = d_in[3];
  const bf16* b1 = (const bf16*)d_in[4];
  const void* w2 = d_in[5];
  const bf16* b2 = (const bf16*)d_in[6];
  const void* w3 = d_in[7];
  const bf16* b3 = (const bf16*)d_in[8];

  const int T = in_sizes[0] / HDIM;              // 8192
  const size_t wtsz = (size_t)NEXP * HH * 2;     // 16.8 MB bf16
  const size_t xbsz = (size_t)T * HDIM * 2;      // 16.8 MB bf16 token copy

  // smallest split count S whose layout fits ws_size (deterministic)
  int S = 64;
  size_t base_need = 0;
  for (int cand = 1; cand <= 64; cand *= 2) {
    size_t rcap = (size_t)2 * T / cand + NEXP * BM;
    size_t ntmx = rcap / BM;
    size_t need = 12288 + (size_t)8 * T * 3 + (size_t)4 * cand * rcap
                + (size_t)4 * cand * ntmx + wtsz + 2 * rcap * HDIM * 2
                + xbsz + 1024;
    if (need <= ws_size) { S = cand; base_need = need; break; }
  }
  const int TS = T / S;
  const int RCAP = 2 * TS + NEXP * BM;
  const int NTMAX = RCAP / BM;                   // multiple of 8 (NEXP)
  // merged trans (one dispatch, 3 contiguous wt buffers) if 2 extra wt fit
  const bool merged = (base_need + 2 * wtsz <= ws_size);

  char* ws = (char*)d_ws;
  size_t ofs = 0;
  int*   meta   = (int*)(ws + ofs);   ofs += 12288;
  int*   sel_e  = (int*)(ws + ofs);   ofs += (size_t)8 * T;
  float* sel_w  = (float*)(ws + ofs); ofs += (size_t)8 * T;
  int*   pos_of = (int*)(ws + ofs);   ofs += (size_t)8 * T;
  int*   list   = (int*)(ws + ofs);   ofs += (size_t)4 * S * RCAP;
  int*   row_e  = (int*)(ws + ofs);   ofs += (size_t)4 * S * NTMAX;
  ofs = (ofs + 255) & ~(size_t)255;
  bf16* wt0 = (bf16*)(ws + ofs); ofs += merged ? 3 * wtsz : wtsz;  // contiguous x3
  bf16* h1  = (bf16*)(ws + ofs); ofs += (size_t)RCAP * HDIM * 2;   // reused per split
  bf16* h2  = (bf16*)(ws + ofs); ofs += (size_t)RCAP * HDIM * 2;
  bf16* xb  = (bf16*)(ws + ofs); ofs += xbsz;                      // bf16 tokens (fp32-x only)
  bf16* wt1 = merged ? wt0 + NEXP * HH : wt0;
  bf16* wt2 = merged ? wt0 + 2 * NEXP * HH : wt0;

  int* flags = meta + 2048;

  k_sniff<<<17, 256, 0, stream>>>((const ushort_t*)x, 32768,
                                  (const ushort_t*)gw, HDIM * NEXP,
                                  (const ushort_t*)w1, 32768,
                                  (const ushort_t*)w2, 32768,
                                  (const ushort_t*)w3, 32768, meta);
  k_router<<<(T + 7) / 8, 512, 0, stream>>>(x, gw, gb, d_out, xb, sel_e, sel_w,
                                            meta, TS, T);
  k_offsets<<<S, 256, 0, stream>>>(sel_e, meta, list, row_e, RCAP, NTMAX, TS);
  {
    int sbd = TS < 256 ? TS : 256;               // block lies within one split
    k_scatter<<<T / sbd, sbd, 0, stream>>>(sel_e, meta, list, pos_of, T, TS, RCAP);
  }

  dim3 gg(HDIM / BN, NTMAX);                     // (4, 72) at S=1
  const bf16* xbf = (const bf16*)x;   // valid when x is bf16 (runtime flag decides)

  if (merged) {
    dim3 tgm(HDIM / 32, HDIM / 32, 3 * NEXP);
    k_trans<<<tgm, 256, 0, stream>>>(w1, w2, w3, flags, wt0);
  }
  for (int s = 0; s < S; s++) {
    const int* lst = list + (size_t)s * RCAP;
    const int* re  = row_e + (size_t)s * NTMAX;
    const int* nt  = meta + 2560 + s;
    dim3 tg1(HDIM / 32, HDIM / 32, NEXP);
    if (!merged) k_trans<<<tg1, 256, 0, stream>>>(w1, w1, w1, flags + 0, wt0);
    k_gemm<true,  true ><<<gg, 512, 0, stream>>>(xbf, xb, lst, re, nt, wt0, b1, h1, flags, T - 1);
    if (!merged) k_trans<<<tg1, 256, 0, stream>>>(w2, w2, w2, flags + 1, wt1);
    k_gemm<false, true ><<<gg, 512, 0, stream>>>(h1, nullptr, nullptr, re, nt, wt1, b2, h2, flags, T - 1);
    if (!merged) k_trans<<<tg1, 256, 0, stream>>>(w3, w3, w3, flags + 2, wt2);
    k_gemm<false, false><<<gg, 512, 0, stream>>>(h2, nullptr, nullptr, re, nt, wt2, b3, h1, flags, T - 1);
    k_combine<<<TS, 256, 0, stream>>>(h1, pos_of + (size_t)2 * s * TS,
                                      sel_w + (size_t)2 * s * TS,
                                      d_out, (size_t)s * TS * HDIM, meta, RCAP - 1);
  }
}

// Round 11
// 415.626 us; speedup vs baseline: 1.0751x; 1.0751x over previous
//
#include <hip/hip_runtime.h>
#include <hip/hip_bf16.h>

// SparseMOE on MI355X — round 18: revert GEMM to r15 (proven 62us) + tail opts.
// Post-mortem r17 (447 us): 256^2 tile REGRESSED (62->70us/gemm). FETCH fell
// 114->84MB (traffic halving verified) but 96KB LDS -> 1 block/CU: 288 blocks
// = 2-round makespan w/ 32-block tail + no cross-block stall hiding; MfmaUtil
// 19.7%. Also the r17 roofline claim was wrong: 604MB at 134GB/s/CU = ~18us
// << 62us -> 128^2 was stall-bound (~900cy/K-step), not staging-BW-bound.
// This round:
//  * k_gemm: byte-identical revert to r15/r16 (128^2, 4-buf, 1 barrier,
//    counted vmcnt, swizzle, LDS epilogue) — best measured (62us).
//  * k_combine: 16B uint4 loads/stores, 2 tokens/block (was 8B, 1 token).
//  * k_router: 16B x loads (2 j-iters x 8 elems), xb written as uint4.
//  * k_offsets: 512 threads (single-block kernel at S=1 — halve serial loops).
// sniff-merge / merged trans / scatter unchanged (proven r16).

#define HDIM 1024
#define NEXP 8
#define BM 128
#define BN 128
#define BK 32
#define HH ((size_t)HDIM * HDIM)

typedef __hip_bfloat16 bf16;
typedef unsigned short ushort_t;
typedef __attribute__((ext_vector_type(8))) short bf16x8;
typedef __attribute__((ext_vector_type(4))) float f32x4;

__device__ __forceinline__ float bflo(unsigned u) { return __uint_as_float(u << 16); }
__device__ __forceinline__ float bfhi(unsigned u) { return __uint_as_float(u & 0xffff0000u); }
__device__ __forceinline__ unsigned short f2bfu(float f) {
  bf16 h = __float2bfloat16(f);
  return *reinterpret_cast<unsigned short*>(&h);
}
__device__ __forceinline__ int iclamp(int v, int lo, int hi) {
  return v < lo ? lo : (v > hi ? hi : v);
}

// async global->LDS, 16B/lane; LDS dest is wave-uniform base + lane*16
__device__ __forceinline__ void async_cp16(const void* g, void* l) {
  __builtin_amdgcn_global_load_lds((const __attribute__((address_space(1))) void*)g,
                                   (__attribute__((address_space(3))) void*)l,
                                   16, 0, 0);
}

// load 4 consecutive elements (idx multiple of 4) as floats, dtype-flagged
__device__ __forceinline__ void ld4f(const void* base, size_t idx, bool f32, float o[4]) {
  if (f32) {
    float4 v = *(const float4*)((const float*)base + idx);
    o[0] = v.x; o[1] = v.y; o[2] = v.z; o[3] = v.w;
  } else {
    uint2 v = *(const uint2*)((const unsigned short*)base + idx);
    o[0] = bflo(v.x); o[1] = bfhi(v.x); o[2] = bflo(v.y); o[3] = bfhi(v.y);
  }
}

// ------- sniff + init merged: blocks 0-4 sniff (plain store), 5-16 zero meta -------
__global__ void k_sniff(const ushort_t* a0, int n0, const ushort_t* a1, int n1,
                        const ushort_t* a2, int n2, const ushort_t* a3, int n3,
                        const ushort_t* a4, int n4, int* __restrict__ meta) {
  int b = blockIdx.x;
  int tid = threadIdx.x;
  if (b >= 5) {
    int idx = (b - 5) * 256 + tid;           // 0..3071 covers 3067 items
    int i = idx < 2048 ? idx : idx + 5;      // skip flags range [2048,2053)
    if (i < 3072) meta[i] = 0;
    return;
  }
  const ushort_t* a = b == 0 ? a0 : b == 1 ? a1 : b == 2 ? a2 : b == 3 ? a3 : a4;
  int n = b == 0 ? n0 : b == 1 ? n1 : b == 2 ? n2 : b == 3 ? n3 : n4;
  int hits = 0;
  for (int i = tid; i < n; i += 256) {
    ushort_t v = a[i];
    if ((v & 0x7F80) == 0x7F80) hits++;      // bf16 NaN/Inf exponent pattern
  }
  __shared__ int red[256];
  red[tid] = hits;
  __syncthreads();
  for (int off = 128; off >= 1; off >>= 1) {
    if (tid < off) red[tid] += red[tid + off];
    __syncthreads();
  }
  if (tid == 0) meta[2048 + b] = red[0];     // plain store
}

// ---------------- router: 1 wave/token, LDS-transposed gate, NO atomics ----------------
// meta ints: [0,512)=cnt[s][e], [512,1024)=fill[s][e], [1024,1536)=segbase[s][e],
//            [2048,2053)=dtype flags {x,gw,w1,w2,w3}, [2560,2624)=ntiles[s]
__global__ __launch_bounds__(512) void k_router(
    const void* __restrict__ x, const void* __restrict__ gw,
    const bf16* __restrict__ gb, void* __restrict__ dout, bf16* __restrict__ xb,
    int* __restrict__ sel_e, float* __restrict__ sel_w,
    int* __restrict__ meta, int TS, int T) {
  __shared__ float sgT[NEXP][HDIM];            // 32 KB gate, TRANSPOSED [e][h]
  const int* flags = meta + 2048;
  bool fx = flags[0] != 0, fgw = flags[1] != 0;
  int tid = threadIdx.x;

#pragma unroll
  for (int r = 0; r < 2; r++) {
    int h = r * 512 + tid;
    float g[8];
    ld4f(gw, (size_t)h * NEXP, fgw, g);
    ld4f(gw, (size_t)h * NEXP + 4, fgw, g + 4);
#pragma unroll
    for (int e = 0; e < NEXP; e++) sgT[e][h] = g[e];
  }
  __syncthreads();

  int wave = tid >> 6, lane = tid & 63;
  int t = blockIdx.x * 8 + wave;

  double acc[NEXP];
#pragma unroll
  for (int e = 0; e < NEXP; e++) acc[e] = 0.0;

  if (t < T) {
    // 16B loads: 2 iterations x 8 elems/lane
#pragma unroll
    for (int j = 0; j < 2; j++) {
      int h = j * 512 + lane * 8;
      float xf[8];
      ld4f(x, (size_t)t * HDIM + h, fx, xf);
      ld4f(x, (size_t)t * HDIM + h + 4, fx, xf + 4);
      if (fx) {   // only materialize bf16 copy when x is fp32 (one uint4 store)
        uint4 ov;
        ov.x = (unsigned)f2bfu(xf[0]) | ((unsigned)f2bfu(xf[1]) << 16);
        ov.y = (unsigned)f2bfu(xf[2]) | ((unsigned)f2bfu(xf[3]) << 16);
        ov.z = (unsigned)f2bfu(xf[4]) | ((unsigned)f2bfu(xf[5]) << 16);
        ov.w = (unsigned)f2bfu(xf[6]) | ((unsigned)f2bfu(xf[7]) << 16);
        *(uint4*)((unsigned short*)xb + (size_t)t * HDIM + h) = ov;
      }
#pragma unroll
      for (int i = 0; i < 8; i += 4) {
#pragma unroll
        for (int e = 0; e < NEXP; e++) {
          float4 g0 = *(const float4*)&sgT[e][h + i];
          acc[e] += (double)xf[i] * (double)g0.x + (double)xf[i + 1] * (double)g0.y
                  + (double)xf[i + 2] * (double)g0.z + (double)xf[i + 3] * (double)g0.w;
        }
      }
    }
  }

#pragma unroll
  for (int off = 32; off >= 1; off >>= 1) {
#pragma unroll
    for (int e = 0; e < NEXP; e++) acc[e] += __shfl_down(acc[e], off);
  }

  if (lane == 0 && t < T) {
    double l[NEXP];
#pragma unroll
    for (int e = 0; e < NEXP; e++) l[e] = acc[e] + (double)__bfloat162float(gb[e]);
    size_t lo = (size_t)T * HDIM + (size_t)t * NEXP;
    if (fx) {
      float* lp = (float*)dout + lo;
#pragma unroll
      for (int e = 0; e < NEXP; e++) lp[e] = (float)l[e];
    } else {
      unsigned short* lp = (unsigned short*)dout + lo;
#pragma unroll
      for (int e = 0; e < NEXP; e++) lp[e] = f2bfu((float)l[e]);
    }
    int i1 = 0; double v1 = l[0];
#pragma unroll
    for (int e = 1; e < NEXP; e++) if (l[e] > v1) { v1 = l[e]; i1 = e; }
    int i2 = -1; double v2 = -1e300;
#pragma unroll
    for (int e = 0; e < NEXP; e++) if (e != i1 && l[e] > v2) { v2 = l[e]; i2 = e; }
    if (i2 < 0) i2 = (i1 + 1) & 7;               // defensive
    float w1 = 1.0f / (1.0f + __expf((float)(v2 - v1)));
    sel_e[2 * t] = i1; sel_e[2 * t + 1] = i2;
    sel_w[2 * t] = w1; sel_w[2 * t + 1] = 1.0f - w1;
  }
}

// ------- offsets: histogram sel_e locally, BM-aligned segments, row map, pads -------
// 512 threads (single block at S=1 — serial loops halved vs 256).
__global__ __launch_bounds__(512) void k_offsets(
    const int* __restrict__ sel_e, int* __restrict__ meta,
    int* __restrict__ list, int* __restrict__ row_e,
    int RCAP, int NTMAX, int TS) {
  int s = blockIdx.x;
  __shared__ int base[NEXP + 1];
  __shared__ int wsum[8][NEXP];
  int tid = threadIdx.x;

  int cnt[NEXP];
#pragma unroll
  for (int e = 0; e < NEXP; e++) cnt[e] = 0;
  const int* se = sel_e + (size_t)2 * s * TS;
  for (int i = tid; i < 2 * TS; i += 512) {
    int v = se[i];
#pragma unroll
    for (int e = 0; e < NEXP; e++) cnt[e] += (v == e) ? 1 : 0;
  }
#pragma unroll
  for (int off = 32; off >= 1; off >>= 1)
#pragma unroll
    for (int e = 0; e < NEXP; e++) cnt[e] += __shfl_down(cnt[e], off);
  int lane = tid & 63, wave = tid >> 6;
  if (lane == 0) {
#pragma unroll
    for (int e = 0; e < NEXP; e++) wsum[wave][e] = cnt[e];
  }
  __syncthreads();

  if (tid == 0) {
    int b = 0;
    for (int e = 0; e < NEXP; e++) {
      int ce = 0;
#pragma unroll
      for (int w = 0; w < 8; w++) ce += wsum[w][e];
      base[e] = b;
      meta[s * 8 + e] = ce;
      meta[512 + s * 8 + e] = b;               // fill counter
      meta[1024 + s * 8 + e] = b;              // segment base (rows)
      b = (b + ce + BM - 1) & ~(BM - 1);
    }
    base[NEXP] = b;
    meta[2560 + s] = b / BM;                   // total tiles this split
  }
  __syncthreads();

  for (int r = tid; r < NTMAX; r += 512) {
    int rs = r * BM;
    int e = 0;
    for (int q = 1; q < NEXP; q++) if (rs >= base[q]) e = q;
    row_e[s * NTMAX + r] = e;
  }
  int* ls = list + (size_t)s * RCAP;
  for (int e = 0; e < NEXP; e++) {
    int ce = 0;
#pragma unroll
    for (int w = 0; w < 8; w++) ce += wsum[w][e];
    for (int p = base[e] + ce + tid; p < base[e + 1]; p += 512)
      ls[p] = s * TS;        // pad rows gather a valid token; never combined
  }
}

// ------- scatter: two-level (LDS bin ranks + 8 global RMWs/block) -------
__global__ void k_scatter(const int* __restrict__ sel_e, int* __restrict__ meta,
                          int* __restrict__ list, int* __restrict__ pos_of,
                          int T, int TS, int RCAP) {
  __shared__ int lcnt[NEXP];
  __shared__ int lbase[NEXP];
  int tid = threadIdx.x;
  if (tid < NEXP) lcnt[tid] = 0;
  __syncthreads();
  int t = blockIdx.x * blockDim.x + tid;
  int s = (int)(((long long)blockIdx.x * blockDim.x) / TS);   // uniform per block
  int e0 = sel_e[2 * t], e1 = sel_e[2 * t + 1];
  int r0 = atomicAdd(&lcnt[e0], 1);
  int r1 = atomicAdd(&lcnt[e1], 1);
  __syncthreads();
  if (tid < NEXP) lbase[tid] = atomicAdd(&meta[512 + s * 8 + tid], lcnt[tid]);
  __syncthreads();
  int p0 = lbase[e0] + r0;
  int p1 = lbase[e1] + r1;
  if (p0 >= 0 && p0 < RCAP) list[(size_t)s * RCAP + p0] = t;
  if (p1 >= 0 && p1 < RCAP) list[(size_t)s * RCAP + p1] = t;
  pos_of[2 * t] = p0;
  pos_of[2 * t + 1] = p1;
}

// -------- transpose+convert, up to 3 layers in one dispatch: layer = z>>3 --------
__global__ void k_trans(const void* __restrict__ wa, const void* __restrict__ wb,
                        const void* __restrict__ wc, const int* __restrict__ flags,
                        bf16* __restrict__ wt) {
  int z = blockIdx.z;
  int layer = z >> 3, e = z & 7;
  const void* w = layer == 0 ? wa : layer == 1 ? wb : wc;
  bool fW = flags[2 + layer] != 0;
  bf16* wtl = wt + (size_t)layer * NEXP * HH;
  __shared__ unsigned short tile[32][33];
  int tid = threadIdx.x;
  int r = tid >> 3, c4 = (tid & 7) * 4;
  int R0 = blockIdx.y * 32, C0 = blockIdx.x * 32;
  float v[4];
  ld4f(w, (size_t)e * HH + (size_t)(R0 + r) * HDIM + C0 + c4, fW, v);
  tile[c4 + 0][r] = f2bfu(v[0]);
  tile[c4 + 1][r] = f2bfu(v[1]);
  tile[c4 + 2][r] = f2bfu(v[2]);
  tile[c4 + 3][r] = f2bfu(v[3]);
  __syncthreads();
  uint2 ov;
  ov.x = (unsigned)tile[r][c4 + 0] | ((unsigned)tile[r][c4 + 1] << 16);
  ov.y = (unsigned)tile[r][c4 + 2] | ((unsigned)tile[r][c4 + 3] << 16);
  *(uint2*)((unsigned short*)wtl + (size_t)e * HH + (size_t)(C0 + r) * HDIM + R0 + c4) = ov;
}

// ---- MFMA GEMM: 4-buf single-barrier pipeline, counted vmcnt, swizzle, setprio ----
// Byte-identical to r15/r16 (proven 62 us). A is ALWAYS bf16.
template <bool GATHER, bool RELU>
__global__ __launch_bounds__(256) void k_gemm(
    const bf16* __restrict__ A, const bf16* __restrict__ Axb,
    const int* __restrict__ list,
    const int* __restrict__ row_e, const int* __restrict__ ntiles,
    const bf16* __restrict__ wt, const bf16* __restrict__ bias,
    bf16* __restrict__ C, const int* __restrict__ flags, int Tm1) {
  // XCD swizzle: ids sharing tm are gridDim.y apart (144 % 8 == 0 -> same XCD).
  int id = blockIdx.y * gridDim.x + blockIdx.x;
  int tm = id % gridDim.y;
  int tn = id / gridDim.y;
  if (tm >= *ntiles) return;
  int e = row_e[tm];
  int row0 = tm * BM;
  const bf16* Ause = (GATHER && flags[0] != 0) ? Axb : A;  // fp32 x -> bf16 copy

  // 4 buffers x (A 8KB + B 8KB) = 64 KB; chunk-swizzled:
  // physical [row][c] holds logical [row][c^((row>>1)&3)]
  const int BUF = (BM + BN) * BK;                          // 8192 ushorts
  __shared__ __align__(16) unsigned short smem[4 * (BM + BN) * BK];

  int tid = threadIdx.x;
  int lane = tid & 63, wave = tid >> 6;
  // staging: lane -> row base+(lane>>2), chunk lane&3 (16B chunks of 64B row);
  // inverse-swizzled source chunk: (lane&3)^((row>>1)&3) = (lane&3)^((lane>>3)&3)
  int ksw = ((lane & 3) ^ ((lane >> 3) & 3)) * 8;   // elems
  int r0 = wave * 32 + (lane >> 2);

  const unsigned short* pb0 = (const unsigned short*)wt + (size_t)e * HH
                            + (size_t)(tn * BN + r0) * HDIM + ksw;
  const unsigned short* pb1 = pb0 + (size_t)16 * HDIM;
  const unsigned short* pa0;
  const unsigned short* pa1;
  if (GATHER) {
    // per-lane global source is legal for global_load_lds (measured m104/m108)
    int t0 = iclamp(list[row0 + r0], 0, Tm1);
    int t1 = iclamp(list[row0 + r0 + 16], 0, Tm1);
    pa0 = (const unsigned short*)Ause + (size_t)t0 * HDIM + ksw;
    pa1 = (const unsigned short*)Ause + (size_t)t1 * HDIM + ksw;
  } else {
    pa0 = (const unsigned short*)Ause + (size_t)(row0 + r0) * HDIM + ksw;
    pa1 = pa0 + (size_t)16 * HDIM;
  }
  unsigned short* laD0 = smem + (wave * 32) * BK;            // + p*BUF
  unsigned short* laD1 = laD0 + 16 * BK;
  unsigned short* lbD0 = smem + BM * BK + (wave * 32) * BK;  // + p*BUF
  unsigned short* lbD1 = lbD0 + 16 * BK;

#define STAGE(pb, ktt)                                         \
  do {                                                         \
    int _o = (pb) * BUF;                                       \
    async_cp16(pa0 + (size_t)(ktt) * BK, laD0 + _o);           \
    async_cp16(pa1 + (size_t)(ktt) * BK, laD1 + _o);           \
    async_cp16(pb0 + (size_t)(ktt) * BK, lbD0 + _o);           \
    async_cp16(pb1 + (size_t)(ktt) * BK, lbD1 + _o);           \
  } while (0)

  f32x4 acc[4][4];
#pragma unroll
  for (int i = 0; i < 4; i++)
#pragma unroll
    for (int j = 0; j < 4; j++) acc[i][j] = (f32x4){0.f, 0.f, 0.f, 0.f};

  int lm = lane & 15, quad = lane >> 4;
  int am = (wave & 1) * 64, bn = (wave >> 1) * 64;
  // ds_read chunk: logical chunk = quad, row ≡ lm (mod 16) -> phys = quad^((lm>>1)&3)
  int rdc = (quad ^ ((lm >> 1) & 3)) * 8;            // elems

  STAGE(0, 0);
  STAGE(1, 1);
  STAGE(2, 2);

  const int NK = HDIM / BK;                          // 32
  for (int kt = 0; kt < NK; ++kt) {
    int p = kt & 3;
    // counted wait: tile kt's 4 stages retired (own-wave); single barrier then
    // makes all waves' tile-kt data mutually visible. Stage kt+3 goes into the
    // buffer of tile kt-1, whose reads every wave completed BEFORE this barrier
    // (MFMA's lgkmcnt drained the ds_reads) -> race-free with one barrier.
    if (kt < NK - 2)       asm volatile("s_waitcnt vmcnt(8)" ::: "memory");
    else if (kt == NK - 2) asm volatile("s_waitcnt vmcnt(4)" ::: "memory");
    else                   asm volatile("s_waitcnt vmcnt(0)" ::: "memory");
    __builtin_amdgcn_sched_barrier(0);
    __builtin_amdgcn_s_barrier();
    __builtin_amdgcn_sched_barrier(0);
    if (kt + 3 < NK) STAGE((kt + 3) & 3, kt + 3);

    int o = p * BUF;
    bf16x8 af[4], bfr[4];
#pragma unroll
    for (int i = 0; i < 4; i++)
      af[i] = *(const bf16x8*)&smem[o + (am + i * 16 + lm) * BK + rdc];
#pragma unroll
    for (int j = 0; j < 4; j++)
      bfr[j] = *(const bf16x8*)&smem[o + BM * BK + (bn + j * 16 + lm) * BK + rdc];
    __builtin_amdgcn_s_setprio(1);
#pragma unroll
    for (int i = 0; i < 4; i++)
#pragma unroll
      for (int j = 0; j < 4; j++)
        acc[i][j] = __builtin_amdgcn_mfma_f32_16x16x32_bf16(af[i], bfr[j], acc[i][j], 0, 0, 0);
    __builtin_amdgcn_s_setprio(0);
  }
#undef STAGE

  // ---- epilogue: bias+relu -> LDS (first 32KB, free now) -> coalesced stores ----
  __syncthreads();                       // all waves done with MFMA/LDS reads
  unsigned short* cst = smem;            // 128x128 ushort = 32 KB
#pragma unroll
  for (int j = 0; j < 4; j++) {
    int col = bn + j * 16 + lm;          // tile-local col
    float bv = __bfloat162float(bias[e * HDIM + tn * BN + col]);  // zeros: dtype-safe
#pragma unroll
    for (int i = 0; i < 4; i++) {
      int rowb = am + i * 16 + quad * 4;
#pragma unroll
      for (int rr = 0; rr < 4; rr++) {
        float v = acc[i][j][rr] + bv;
        if (RELU) v = fmaxf(v, 0.f);
        cst[(rowb + rr) * BN + col] = f2bfu(v);
      }
    }
  }
  __syncthreads();
  {
    unsigned short* Cg = (unsigned short*)C;
#pragma unroll
    for (int it = 0; it < 8; it++) {
      int o = it * 4096 + tid * 16;      // byte offset into 32KB tile
      int row = o >> 8;                  // 256 B per row
      int cole = (o & 255) >> 1;         // element col within tile
      uint4 v = *(const uint4*)((const char*)cst + o);
      *(uint4*)&Cg[(size_t)(row0 + row) * HDIM + tn * BN + cole] = v;
    }
  }
}

// ------- weighted combine: 2 tokens/block, 16B loads/stores -------
__global__ void k_combine(const bf16* __restrict__ y, const int* __restrict__ pos_of,
                          const float* __restrict__ sel_w, void* __restrict__ dout,
                          size_t out_elem_off, const int* __restrict__ meta, int Pm1) {
  bool fx = meta[2048] != 0;                   // out dtype follows x
  int tid = threadIdx.x;
  int t = blockIdx.x * 2 + (tid >> 7);
  int l = tid & 127;
  int p0 = iclamp(pos_of[2 * t], 0, Pm1);
  int p1 = iclamp(pos_of[2 * t + 1], 0, Pm1);
  float w0 = sel_w[2 * t], w1 = sel_w[2 * t + 1];
  int h = l * 8;
  uint4 a = *(const uint4*)((const unsigned short*)y + (size_t)p0 * HDIM + h);
  uint4 b = *(const uint4*)((const unsigned short*)y + (size_t)p1 * HDIM + h);
  float o0 = w0 * bflo(a.x) + w1 * bflo(b.x);
  float o1 = w0 * bfhi(a.x) + w1 * bfhi(b.x);
  float o2 = w0 * bflo(a.y) + w1 * bflo(b.y);
  float o3 = w0 * bfhi(a.y) + w1 * bfhi(b.y);
  float o4 = w0 * bflo(a.z) + w1 * bflo(b.z);
  float o5 = w0 * bfhi(a.z) + w1 * bfhi(b.z);
  float o6 = w0 * bflo(a.w) + w1 * bflo(b.w);
  float o7 = w0 * bfhi(a.w) + w1 * bfhi(b.w);
  size_t off = out_elem_off + (size_t)t * HDIM + h;
  if (fx) {
    float4 v0 = { o0, o1, o2, o3 };
    float4 v1 = { o4, o5, o6, o7 };
    *(float4*)((float*)dout + off) = v0;
    *(float4*)((float*)dout + off + 4) = v1;
  } else {
    uint4 ov;
    ov.x = (unsigned)f2bfu(o0) | ((unsigned)f2bfu(o1) << 16);
    ov.y = (unsigned)f2bfu(o2) | ((unsigned)f2bfu(o3) << 16);
    ov.z = (unsigned)f2bfu(o4) | ((unsigned)f2bfu(o5) << 16);
    ov.w = (unsigned)f2bfu(o6) | ((unsigned)f2bfu(o7) << 16);
    *(uint4*)((unsigned short*)dout + off) = ov;
  }
}

extern "C" void kernel_launch(void* const* d_in, const int* in_sizes, int n_in,
                              void* d_out, int out_size, void* d_ws, size_t ws_size,
                              hipStream_t stream) {
  const void* x  = d_in[0];
  const void* gw = d_in[1];
  const bf16* gb = (const bf16*)d_in[2];
  const void* w1 = d_in[3];
  const bf16* b1 = (const bf16*)d_in[4];
  const void* w2 = d_in[5];
  const bf16* b2 = (const bf16*)d_in[6];
  const void* w3 = d_in[7];
  const bf16* b3 = (const bf16*)d_in[8];

  const int T = in_sizes[0] / HDIM;              // 8192
  const size_t wtsz = (size_t)NEXP * HH * 2;     // 16.8 MB bf16
  const size_t xbsz = (size_t)T * HDIM * 2;      // 16.8 MB bf16 token copy

  // smallest split count S whose layout fits ws_size (deterministic)
  int S = 64;
  size_t base_need = 0;
  for (int cand = 1; cand <= 64; cand *= 2) {
    size_t rcap = (size_t)2 * T / cand + NEXP * BM;
    size_t ntmx = rcap / BM;
    size_t need = 12288 + (size_t)8 * T * 3 + (size_t)4 * cand * rcap
                + (size_t)4 * cand * ntmx + wtsz + 2 * rcap * HDIM * 2
                + xbsz + 1024;
    if (need <= ws_size) { S = cand; base_need = need; break; }
  }
  const int TS = T / S;
  const int RCAP = 2 * TS + NEXP * BM;
  const int NTMAX = RCAP / BM;                   // multiple of 8 (NEXP)
  // merged trans (one dispatch, 3 contiguous wt buffers) if 2 extra wt fit
  const bool merged = (base_need + 2 * wtsz <= ws_size);

  char* ws = (char*)d_ws;
  size_t ofs = 0;
  int*   meta   = (int*)(ws + ofs);   ofs += 12288;
  int*   sel_e  = (int*)(ws + ofs);   ofs += (size_t)8 * T;
  float* sel_w  = (float*)(ws + ofs); ofs += (size_t)8 * T;
  int*   pos_of = (int*)(ws + ofs);   ofs += (size_t)8 * T;
  int*   list   = (int*)(ws + ofs);   ofs += (size_t)4 * S * RCAP;
  int*   row_e  = (int*)(ws + ofs);   ofs += (size_t)4 * S * NTMAX;
  ofs = (ofs + 255) & ~(size_t)255;
  bf16* wt0 = (bf16*)(ws + ofs); ofs += merged ? 3 * wtsz : wtsz;  // contiguous x3
  bf16* h1  = (bf16*)(ws + ofs); ofs += (size_t)RCAP * HDIM * 2;   // reused per split
  bf16* h2  = (bf16*)(ws + ofs); ofs += (size_t)RCAP * HDIM * 2;
  bf16* xb  = (bf16*)(ws + ofs); ofs += xbsz;                      // bf16 tokens (fp32-x only)
  bf16* wt1 = merged ? wt0 + NEXP * HH : wt0;
  bf16* wt2 = merged ? wt0 + 2 * NEXP * HH : wt0;

  int* flags = meta + 2048;

  k_sniff<<<17, 256, 0, stream>>>((const ushort_t*)x, 32768,
                                  (const ushort_t*)gw, HDIM * NEXP,
                                  (const ushort_t*)w1, 32768,
                                  (const ushort_t*)w2, 32768,
                                  (const ushort_t*)w3, 32768, meta);
  k_router<<<(T + 7) / 8, 512, 0, stream>>>(x, gw, gb, d_out, xb, sel_e, sel_w,
                                            meta, TS, T);
  k_offsets<<<S, 512, 0, stream>>>(sel_e, meta, list, row_e, RCAP, NTMAX, TS);
  {
    int sbd = TS < 256 ? TS : 256;               // block lies within one split
    k_scatter<<<T / sbd, sbd, 0, stream>>>(sel_e, meta, list, pos_of, T, TS, RCAP);
  }

  dim3 gg(HDIM / BN, NTMAX);                     // (8, 144) at S=1
  const bf16* xbf = (const bf16*)x;   // valid when x is bf16 (runtime flag decides)

  if (merged) {
    dim3 tgm(HDIM / 32, HDIM / 32, 3 * NEXP);
    k_trans<<<tgm, 256, 0, stream>>>(w1, w2, w3, flags, wt0);
  }
  for (int s = 0; s < S; s++) {
    const int* lst = list + (size_t)s * RCAP;
    const int* re  = row_e + (size_t)s * NTMAX;
    const int* nt  = meta + 2560 + s;
    dim3 tg1(HDIM / 32, HDIM / 32, NEXP);
    if (!merged) k_trans<<<tg1, 256, 0, stream>>>(w1, w1, w1, flags + 0, wt0);
    k_gemm<true,  true ><<<gg, 256, 0, stream>>>(xbf, xb, lst, re, nt, wt0, b1, h1, flags, T - 1);
    if (!merged) k_trans<<<tg1, 256, 0, stream>>>(w2, w2, w2, flags + 1, wt1);
    k_gemm<false, true ><<<gg, 256, 0, stream>>>(h1, nullptr, nullptr, re, nt, wt1, b2, h2, flags, T - 1);
    if (!merged) k_trans<<<tg1, 256, 0, stream>>>(w3, w3, w3, flags + 2, wt2);
    k_gemm<false, false><<<gg, 256, 0, stream>>>(h2, nullptr, nullptr, re, nt, wt2, b3, h1, flags, T - 1);
    k_combine<<<TS / 2, 256, 0, stream>>>(h1, pos_of + (size_t)2 * s * TS,
                                          sel_w + (size_t)2 * s * TS,
                                          d_out, (size_t)s * TS * HDIM, meta, RCAP - 1);
  }
}